// Round 1
// baseline (20483.005 us; speedup 1.0000x reference)
//
#include <hip/hip_runtime.h>

#define Bd 64
#define Td 64
#define Sd 128
#define Hd 512
#define Ed 256
#define Vd 10000

__device__ __forceinline__ float fast_tanh(float x) {
  float e = __expf(-2.0f * fabsf(x));
  float r = (1.0f - e) / (1.0f + e);
  return copysignf(r, x);
}
__device__ __forceinline__ float fast_sigmoid(float x) {
  return 1.0f / (1.0f + __expf(-x));
}

// copy h0 input (L,B,H) into working h buffers
__global__ void k_init(const float* __restrict__ h0_in, float* __restrict__ h0b,
                       float* __restrict__ h1b) {
  int b = blockIdx.x, j = threadIdx.x;
  h0b[b * Hd + j] = h0_in[(0 * Bd + b) * Hd + j];
  h1b[b * Hd + j] = h0_in[(1 * Bd + b) * Hd + j];
}

// C[M,N] = A[M,K] @ W[N,K]^T (+bias). SWAP: out row m=(t*64+b) -> (b*T+t).
template <bool SWAP, bool BIAS>
__global__ void k_gemm_abt(const float* __restrict__ A, const float* __restrict__ W,
                           const float* __restrict__ bias, float* __restrict__ C,
                           int M, int N, int K) {
  __shared__ __align__(16) float As[16][64];
  __shared__ __align__(16) float Ws[16][64];
  int m0 = blockIdx.x * 64, n0 = blockIdx.y * 64;
  int tid = threadIdx.x;
  int tx = tid & 15, ty = tid >> 4;
  float acc[4][4] = {};
  for (int k0 = 0; k0 < K; k0 += 16) {
#pragma unroll
    for (int i = 0; i < 4; i++) {
      int e = tid + i * 256;
      int r = e >> 4, c = e & 15;
      As[c][r] = A[(long)(m0 + r) * K + k0 + c];
    }
#pragma unroll
    for (int i = 0; i < 4; i++) {
      int e = tid + i * 256;
      int r = e >> 4, c = e & 15;
      int n = n0 + r;
      Ws[c][r] = (n < N) ? W[(long)n * K + k0 + c] : 0.0f;
    }
    __syncthreads();
#pragma unroll
    for (int k = 0; k < 16; k++) {
      float a_[4], w_[4];
#pragma unroll
      for (int i = 0; i < 4; i++) a_[i] = As[k][ty * 4 + i];
#pragma unroll
      for (int j = 0; j < 4; j++) w_[j] = Ws[k][tx * 4 + j];
#pragma unroll
      for (int i = 0; i < 4; i++)
#pragma unroll
        for (int j = 0; j < 4; j++) acc[i][j] += a_[i] * w_[j];
    }
    __syncthreads();
  }
#pragma unroll
  for (int i = 0; i < 4; i++) {
    int m = m0 + ty * 4 + i;
#pragma unroll
    for (int j = 0; j < 4; j++) {
      int n = n0 + tx * 4 + j;
      if (n < N) {
        float v = acc[i][j];
        if (BIAS) v += bias[n];
        long idx;
        if (SWAP) {
          int t_ = m >> 6, b_ = m & 63;
          idx = ((long)(b_ * Td + t_)) * N + n;
        } else {
          idx = (long)m * N + n;
        }
        C[idx] = v;
      }
    }
  }
}

// qp[b,n] = sum_k h1[b,k] * Wq[n,k]; grid 32 blocks (16 n each), 256 threads
__global__ void k_qproj(const float* __restrict__ h1, const float* __restrict__ Wq,
                        float* __restrict__ qp) {
  __shared__ __align__(16) float As[64][68];
  int n0 = blockIdx.x * 16;
  int tid = threadIdx.x;
  int b = tid & 63, nl = tid >> 6;
  float acc[4] = {};
  for (int k0 = 0; k0 < Hd; k0 += 64) {
#pragma unroll
    for (int i = 0; i < 16; i++) {
      int e = tid + i * 256;
      int r = e >> 6, c = e & 63;
      As[r][c] = h1[r * Hd + k0 + c];
    }
    __syncthreads();
    for (int k = 0; k < 64; k += 4) {
      float4 a4 = *(const float4*)&As[b][k];
#pragma unroll
      for (int i = 0; i < 4; i++) {
        int n = n0 + nl * 4 + i;
        float4 w4 = *(const float4*)&Wq[n * Hd + k0 + k];
        acc[i] += a4.x * w4.x + a4.y * w4.y + a4.z * w4.z + a4.w * w4.w;
      }
    }
    __syncthreads();
  }
#pragma unroll
  for (int i = 0; i < 4; i++) qp[b * Hd + n0 + nl * 4 + i] = acc[i];
}

// per-b attention: scores = wv . tanh(qp + kproj), masked softmax, context
__global__ void k_attn(const float* __restrict__ qp, const float* __restrict__ kp,
                       const float* __restrict__ enc, const float* __restrict__ wv,
                       const int* __restrict__ vlen, float* __restrict__ ctx) {
  int b = blockIdx.x;
  int tid = threadIdx.x;  // 512
  __shared__ __align__(16) float qs[Hd];
  __shared__ __align__(16) float wvs[Hd];
  __shared__ float sc[Sd];
  __shared__ float red[16];
  qs[tid] = qp[b * Hd + tid];
  wvs[tid] = wv[tid];
  __syncthreads();
  {
    int s = tid >> 2, q = tid & 3;
    float acc = 0.f;
    const float* kpp = &kp[((long)b * Sd + s) * Hd + q * 128];
    const float* qq = &qs[q * 128];
    const float* wq = &wvs[q * 128];
    for (int h = 0; h < 128; h += 4) {
      float4 k4 = *(const float4*)&kpp[h];
      float4 q4 = *(const float4*)&qq[h];
      float4 w4 = *(const float4*)&wq[h];
      acc += w4.x * fast_tanh(q4.x + k4.x);
      acc += w4.y * fast_tanh(q4.y + k4.y);
      acc += w4.z * fast_tanh(q4.z + k4.z);
      acc += w4.w * fast_tanh(q4.w + k4.w);
    }
    acc += __shfl_xor(acc, 1);
    acc += __shfl_xor(acc, 2);
    if (q == 0) sc[s] = (s < vlen[b]) ? acc : -1e6f;
  }
  __syncthreads();
  if (tid < 128) {
    float m = sc[tid];
#pragma unroll
    for (int o = 1; o < 64; o <<= 1) m = fmaxf(m, __shfl_xor(m, o));
    if ((tid & 63) == 0) red[tid >> 6] = m;
  }
  __syncthreads();
  float gm = fmaxf(red[0], red[1]);
  if (tid < 128) {
    float p = __expf(sc[tid] - gm);
    sc[tid] = p;
    float l = p;
#pragma unroll
    for (int o = 1; o < 64; o <<= 1) l += __shfl_xor(l, o);
    if ((tid & 63) == 0) red[8 + (tid >> 6)] = l;
  }
  __syncthreads();
  float gl = red[8] + red[9];
  if (tid < 128) sc[tid] = sc[tid] / gl;
  __syncthreads();
  {
    float acc = 0.f;
    const float* eb = &enc[(long)b * Sd * Hd + tid];
#pragma unroll 4
    for (int s = 0; s < Sd; s++) acc += sc[s] * eb[s * Hd];
    ctx[b * Hd + tid] = acc;
  }
}

// GRU cell. CELL0: input = [ctx | emb[x[:,t]]] (K=768); CELL1: input = h0new (K=512).
// grid 128 blocks (4 j each), 256 threads: thread=(b=tid&63, jl=tid>>6)
template <bool CELL0>
__global__ void k_cell(const float* __restrict__ A1, const float* __restrict__ emb,
                       const int* __restrict__ x, int t, const float* __restrict__ A2,
                       const float* __restrict__ Wih, const float* __restrict__ Whh,
                       const float* __restrict__ bih, const float* __restrict__ bhh,
                       float* __restrict__ hout, float* __restrict__ ys) {
  const int KIH = CELL0 ? (Hd + Ed) : Hd;
  __shared__ __align__(16) float As[64][68];
  __shared__ int xs[64];
  int tid = threadIdx.x;
  int b = tid & 63, jl = tid >> 6;
  int j = blockIdx.x * 4 + jl;
  if (CELL0 && tid < 64) xs[tid] = x[tid * Td + t];
  __syncthreads();
  float pr = 0.f, pz = 0.f, pin = 0.f, phn = 0.f;
  // phase 1: input-hidden
  for (int k0 = 0; k0 < KIH; k0 += 64) {
#pragma unroll
    for (int i = 0; i < 16; i++) {
      int e = tid + i * 256;
      int r = e >> 6, c = e & 63;
      int kg = k0 + c;
      float v;
      if (CELL0) {
        v = (kg < Hd) ? A1[r * Hd + kg] : emb[(long)xs[r] * Ed + (kg - Hd)];
      } else {
        v = A1[r * Hd + kg];
      }
      As[r][c] = v;
    }
    __syncthreads();
    const float* wr = &Wih[(long)j * KIH + k0];
    const float* wz = &Wih[(long)(Hd + j) * KIH + k0];
    const float* wn = &Wih[(long)(2 * Hd + j) * KIH + k0];
    for (int k = 0; k < 64; k += 4) {
      float4 a4 = *(const float4*)&As[b][k];
      float4 r4 = *(const float4*)&wr[k];
      float4 z4 = *(const float4*)&wz[k];
      float4 n4 = *(const float4*)&wn[k];
      pr += a4.x * r4.x + a4.y * r4.y + a4.z * r4.z + a4.w * r4.w;
      pz += a4.x * z4.x + a4.y * z4.y + a4.z * z4.z + a4.w * z4.w;
      pin += a4.x * n4.x + a4.y * n4.y + a4.z * n4.z + a4.w * n4.w;
    }
    __syncthreads();
  }
  // phase 2: hidden-hidden
  for (int k0 = 0; k0 < Hd; k0 += 64) {
#pragma unroll
    for (int i = 0; i < 16; i++) {
      int e = tid + i * 256;
      int r = e >> 6, c = e & 63;
      As[r][c] = A2[r * Hd + k0 + c];
    }
    __syncthreads();
    const float* wr = &Whh[(long)j * Hd + k0];
    const float* wz = &Whh[(long)(Hd + j) * Hd + k0];
    const float* wn = &Whh[(long)(2 * Hd + j) * Hd + k0];
    for (int k = 0; k < 64; k += 4) {
      float4 a4 = *(const float4*)&As[b][k];
      float4 r4 = *(const float4*)&wr[k];
      float4 z4 = *(const float4*)&wz[k];
      float4 n4 = *(const float4*)&wn[k];
      pr += a4.x * r4.x + a4.y * r4.y + a4.z * r4.z + a4.w * r4.w;
      pz += a4.x * z4.x + a4.y * z4.y + a4.z * z4.z + a4.w * z4.w;
      phn += a4.x * n4.x + a4.y * n4.y + a4.z * n4.z + a4.w * n4.w;
    }
    __syncthreads();
  }
  float r = fast_sigmoid(pr + bih[j] + bhh[j]);
  float z = fast_sigmoid(pz + bih[Hd + j] + bhh[Hd + j]);
  float n = fast_tanh(pin + bih[2 * Hd + j] + r * (phn + bhh[2 * Hd + j]));
  float hp = A2[b * Hd + j];
  float hn = (1.f - z) * n + z * hp;
  hout[b * Hd + j] = hn;
  if (ys) ys[((long)t * Bd + b) * Hd + j] = hn;
}

extern "C" void kernel_launch(void* const* d_in, const int* in_sizes, int n_in,
                              void* d_out, int out_size, void* d_ws, size_t ws_size,
                              hipStream_t stream) {
  const int* x = (const int*)d_in[0];
  const float* enc = (const float*)d_in[1];
  const float* h0 = (const float*)d_in[2];
  const int* vlen = (const int*)d_in[3];
  const float* emb = (const float*)d_in[4];
  const float* Wq = (const float*)d_in[5];
  const float* Wk = (const float*)d_in[6];
  const float* wv = (const float*)d_in[7];
  const float* W_ih0 = (const float*)d_in[8];
  const float* W_hh0 = (const float*)d_in[9];
  const float* b_ih0 = (const float*)d_in[10];
  const float* b_hh0 = (const float*)d_in[11];
  const float* W_ih1 = (const float*)d_in[12];
  const float* W_hh1 = (const float*)d_in[13];
  const float* b_ih1 = (const float*)d_in[14];
  const float* b_hh1 = (const float*)d_in[15];
  const float* Wd = (const float*)d_in[16];
  const float* bd = (const float*)d_in[17];
  float* out = (float*)d_out;

  float* w = (float*)d_ws;
  float* kp = w;                       // B*S*H = 4194304
  float* qp = kp + (long)Bd * Sd * Hd; // 32768
  float* ctx = qp + Bd * Hd;
  float* h0buf0 = ctx + Bd * Hd;
  float* h0buf1 = h0buf0 + Bd * Hd;
  float* h1buf0 = h0buf1 + Bd * Hd;
  float* h1buf1 = h1buf0 + Bd * Hd;
  float* ys = h1buf1 + Bd * Hd;        // T*B*H = 2097152
  float* h0b[2] = {h0buf0, h0buf1};
  float* h1b[2] = {h1buf0, h1buf1};

  k_init<<<Bd, Hd, 0, stream>>>(h0, h0buf0, h1buf0);
  // k_proj = enc @ Wk^T : M=8192, N=512, K=512
  k_gemm_abt<false, false><<<dim3(128, 8), 256, 0, stream>>>(enc, Wk, nullptr, kp,
                                                             Bd * Sd, Hd, Hd);
  for (int t = 0; t < Td; t++) {
    int cur = t & 1, nxt = cur ^ 1;
    k_qproj<<<32, 256, 0, stream>>>(h1b[cur], Wq, qp);
    k_attn<<<Bd, Hd, 0, stream>>>(qp, kp, enc, wv, vlen, ctx);
    k_cell<true><<<128, 256, 0, stream>>>(ctx, emb, x, t, h0b[cur], W_ih0, W_hh0,
                                          b_ih0, b_hh0, h0b[nxt], nullptr);
    k_cell<false><<<128, 256, 0, stream>>>(h0b[nxt], nullptr, nullptr, t, h1b[cur],
                                           W_ih1, W_hh1, b_ih1, b_hh1, h1b[nxt], ys);
  }
  // logits: ys(T*B,H) @ Wd^T + bd, out[b,t,v]
  k_gemm_abt<true, true><<<dim3(64, 157), 256, 0, stream>>>(ys, Wd, bd, out,
                                                            Td * Bd, Vd, Hd);
}